// Round 12
// baseline (243.155 us; speedup 1.0000x reference)
//
#include <hip/hip_runtime.h>
#include <hip/hip_bf16.h>

#define B 32
#define S 2048
#define E 1024
#define H 1024
#define MASK_VAL -50000.0f

typedef __attribute__((ext_vector_type(8))) short bf16x8_t;
typedef __attribute__((ext_vector_type(4))) float f32x4_t;

__device__ __forceinline__ float fast_tanh(float x) {
    float a = fabsf(x);
    float e = __expf(-2.0f * a);
    float t = (1.0f - e) * __builtin_amdgcn_rcpf(1.0f + e);
    return copysignf(t, x);
}

__device__ __forceinline__ float b2f(short s) {
    return __uint_as_float(((unsigned)(unsigned short)s) << 16);
}

__device__ __forceinline__ bf16x8_t cvt8(const float4 f0, const float4 f1) {
    union { bf16x8_t s8; __hip_bfloat162 h[4]; } u;
    u.h[0] = __float22bfloat162_rn(make_float2(f0.x, f0.y));
    u.h[1] = __float22bfloat162_rn(make_float2(f0.z, f0.w));
    u.h[2] = __float22bfloat162_rn(make_float2(f1.x, f1.y));
    u.h[3] = __float22bfloat162_rn(make_float2(f1.z, f1.w));
    return u.s8;
}

__device__ __forceinline__ void gload16(const void* g, void* l) {
    __builtin_amdgcn_global_load_lds(
        (const __attribute__((address_space(1))) void*)g,
        (__attribute__((address_space(3))) void*)l, 16, 0, 0);
}

// kfused0: [0,1024) W[:, :1024] -> bf16 Wb (coalesced);
//          [1024,2048) dec_proj: one h/block, W_dec row staged in LDS,
//          32 b-dots with 8-lane chunk reduce (coalesced);
//          [2048,2560) enc -> bf16 encb, active 128-row tiles only.
__global__ __launch_bounds__(256) void kfused0(
    const float* __restrict__ W, const float* __restrict__ dec,
    const float* __restrict__ enc, const int* __restrict__ seq,
    __hip_bfloat16* __restrict__ Wb, float* __restrict__ dec_proj,
    __hip_bfloat16* __restrict__ encb)
{
    int blk = blockIdx.x, tid = threadIdx.x;
    if (blk < 1024) {
        int idx = (blk * 256 + tid) * 4;   // over H*E
        int h = idx >> 10, e = idx & 1023;
        float4 f = *(const float4*)(W + (size_t)h * 2048 + e);
        __hip_bfloat162 p0 = __float22bfloat162_rn(make_float2(f.x, f.y));
        __hip_bfloat162 p1 = __float22bfloat162_rn(make_float2(f.z, f.w));
        *reinterpret_cast<__hip_bfloat162*>(Wb + idx)     = p0;
        *reinterpret_cast<__hip_bfloat162*>(Wb + idx + 2) = p1;
    } else if (blk < 2048) {
        int h = blk - 1024;                 // 0..1023
        __shared__ float4 wlds[256];
        wlds[tid] = *(const float4*)(W + (size_t)h * 2048 + 1024 + tid * 4);
        __syncthreads();
        int b = tid >> 3, chunk = tid & 7;  // 32 b x 8 chunks of 128 elems
        const float4* dd = (const float4*)(dec + b * 1024 + chunk * 128);
        float acc = 0.f;
        #pragma unroll
        for (int i = 0; i < 32; ++i) {
            float4 w4 = wlds[chunk * 32 + i];
            float4 d4 = dd[i];
            acc += w4.x * d4.x + w4.y * d4.y + w4.z * d4.z + w4.w * d4.w;
        }
        acc += __shfl_xor(acc, 1);
        acc += __shfl_xor(acc, 2);
        acc += __shfl_xor(acc, 4);
        if (chunk == 0) dec_proj[b * H + h] = acc;
    } else {
        int g = blk - 2048;                 // 512: 16 s-chunks x 32 b
        int c = g & 15, b = g >> 4;
        if (c * 128 >= seq[b]) return;
        size_t base = ((size_t)b * S + c * 128) << 10;
        const float* src = enc + base;
        __hip_bfloat16* dst = encb + base;
        #pragma unroll 4
        for (int it = 0; it < 64; ++it) {
            int idx = it * 2048 + tid * 8;
            float4 f0 = *(const float4*)(src + idx);
            float4 f1 = *(const float4*)(src + idx + 4);
            *(bf16x8_t*)(dst + idx) = cvt8(f0, f1);
        }
    }
}

// K2: 128(s) x 128(h) tile, BK=32, K=1024, 4 waves (2x2), 64x64/wave.
// Same proven 2-phase double-buffer as round 4/11, but LDS shrunk to 32 KiB
// (A/B tile = 8 KiB each, dbuf) -> 5 blocks/CU (20 waves) instead of 2 (8).
// Occupancy is the lever: the per-step vmcnt drain is hidden by 4 other
// resident blocks' compute instead of 1.
// LDS tile layout (chunk-linear, conflict-free): 16B chunk index
//   t(r,c) = r*4 + (c ^ ((r>>1)&3)),  r=row 0..127, c=k-chunk 0..3.
// gload_lds dest stays linear in lane order (base + t*16, t=pass*256+tid);
// the swizzle is applied to the per-lane GLOBAL source (rule m173). ds_read
// at byte r*64 + ((cg ^ ((r>>1)&3))<<4): 8 consecutive rows hit 8 distinct
// 16B slots -> 8 lanes/slot across the wave = b128 baseline (conflict-free).
// MODE 0: A+B via global_load_lds (encb, Wb). MODE 2: A reg-staged from
// fp32 enc (ds_write_b128 at the same swizzled chunk).
// Grid 4096: pair=(bid>>6)*8+(bid&7); ht=(bid>>3)&7 -> the 8 ht-blocks of
// one (b,st) are 8 apart -> same XCD -> A-tile L2 reuse.
template<int MODE>
__global__ __launch_bounds__(256, 5) void k2_mfma(
    const float* __restrict__ enc, const __hip_bfloat16* __restrict__ encb,
    const __hip_bfloat16* __restrict__ Wb, const float* __restrict__ v,
    const float* __restrict__ dec_proj, const int* __restrict__ seq,
    float* __restrict__ part)
{
    const int bid  = blockIdx.x;
    const int pair = (bid >> 6) * 8 + (bid & 7);   // 0..511 = 16 s-tiles x 32 b
    const int ht   = (bid >> 3) & 7;
    const int b    = pair >> 4;
    const int s0   = (pair & 15) * 128;
    if (s0 >= seq[b]) return;
    const int h0 = ht * 128;

    const int tid  = threadIdx.x;
    const int wave = tid >> 6;
    const int lane = tid & 63;
    const int wr = wave >> 1, wc = wave & 1;   // 2x2 wave grid
    const int cr = lane & 15, cg = lane >> 4;

    __shared__ char Al[2][8192];
    __shared__ char Bl[2][8192];

    f32x4_t acc[4][4];
    #pragma unroll
    for (int m = 0; m < 4; ++m)
        #pragma unroll
        for (int n = 0; n < 4; ++n)
            acc[m][n] = (f32x4_t){0.f, 0.f, 0.f, 0.f};

    auto stage = [&](int buf, int kt) {
        #pragma unroll
        for (int pass = 0; pass < 2; ++pass) {
            const int t  = pass * 256 + tid;          // chunk 0..511
            const int r  = t >> 2;                    // 0..127
            const int c3 = (t & 3) ^ ((r >> 1) & 3);  // source k-chunk
            const __hip_bfloat16* bg =
                Wb + (((size_t)(h0 + r)) << 10) + kt * 32 + c3 * 8;
            gload16(bg, &Bl[buf][t * 16]);
            if (MODE == 0) {
                const __hip_bfloat16* ag =
                    encb + (((size_t)b * S + s0 + r) << 10) + kt * 32 + c3 * 8;
                gload16(ag, &Al[buf][t * 16]);
            } else {
                const float* af =
                    enc + (((size_t)b * S + s0 + r) << 10) + kt * 32 + c3 * 8;
                bf16x8_t v8 = cvt8(*(const float4*)af, *(const float4*)(af + 4));
                *(bf16x8_t*)(&Al[buf][t * 16]) = v8;
            }
        }
    };

    stage(0, 0);
    __syncthreads();
    int cur = 0;
    for (int kt = 0; kt < 32; ++kt) {
        if (kt < 31) stage(cur ^ 1, kt + 1);   // flies under the MFMAs below
        bf16x8_t afr[4], bfr[4];
        #pragma unroll
        for (int m = 0; m < 4; ++m) {
            const int arow = wr * 64 + m * 16 + cr;
            afr[m] = *(const bf16x8_t*)(
                &Al[cur][arow * 64 + ((cg ^ ((arow >> 1) & 3)) << 4)]);
            const int brow = wc * 64 + m * 16 + cr;
            bfr[m] = *(const bf16x8_t*)(
                &Bl[cur][brow * 64 + ((cg ^ ((brow >> 1) & 3)) << 4)]);
        }
        #pragma unroll
        for (int m = 0; m < 4; ++m)
            #pragma unroll
            for (int n = 0; n < 4; ++n)
                acc[m][n] = __builtin_amdgcn_mfma_f32_16x16x32_bf16(
                    afr[m], bfr[n], acc[m][n], 0, 0, 0);
        __syncthreads();   // drains vmcnt+lgkmcnt: next buf ready, cur consumed
        cur ^= 1;
    }

    // Epilogue: t = v*tanh(acc + dec_proj); reduce over n frags + 16 cr lanes.
    float vv[4], dp[4];
    #pragma unroll
    for (int n = 0; n < 4; ++n) {
        int h = h0 + wc * 64 + n * 16 + cr;
        vv[n] = v[h];
        dp[n] = dec_proj[b * H + h];
    }
    #pragma unroll
    for (int m = 0; m < 4; ++m) {
        #pragma unroll
        for (int j = 0; j < 4; ++j) {
            float t = 0.f;
            #pragma unroll
            for (int n = 0; n < 4; ++n)
                t += vv[n] * fast_tanh(acc[m][n][j] + dp[n]);
            t += __shfl_xor(t, 1);
            t += __shfl_xor(t, 2);
            t += __shfl_xor(t, 4);
            t += __shfl_xor(t, 8);
            if (cr == 0) {
                int srow = s0 + wr * 64 + m * 16 + cg * 4 + j;
                part[(size_t)(b * S + srow) * 16 + ht * 2 + wc] = t;
            }
        }
    }
}

// K3: sum 16 partials -> logit; masked softmax over s per batch
__global__ __launch_bounds__(256) void k3_softmax(
    const float* __restrict__ part, const int* __restrict__ seq,
    float* __restrict__ attn)
{
    int b = blockIdx.x, tid = threadIdx.x;
    int len = seq[b];
    float vals[8];
    float mx = -3.4e38f;
    #pragma unroll
    for (int i = 0; i < 8; ++i) {
        int s = i * 256 + tid;
        float x = MASK_VAL;
        if (s < len) {
            const f32x4_t* p = (const f32x4_t*)&part[(size_t)(b * S + s) * 16];
            f32x4_t a = p[0], c = p[1], d = p[2], e = p[3];
            x = (a[0] + a[1] + a[2] + a[3]) + (c[0] + c[1] + c[2] + c[3]) +
                (d[0] + d[1] + d[2] + d[3]) + (e[0] + e[1] + e[2] + e[3]);
        }
        vals[i] = x;
        mx = fmaxf(mx, x);
    }
    #pragma unroll
    for (int off = 1; off < 64; off <<= 1) mx = fmaxf(mx, __shfl_xor(mx, off));
    __shared__ float red[8];
    int wave = tid >> 6, lane = tid & 63;
    if (lane == 0) red[wave] = mx;
    __syncthreads();
    mx = fmaxf(fmaxf(red[0], red[1]), fmaxf(red[2], red[3]));
    float e[8];
    float sum = 0.f;
    #pragma unroll
    for (int i = 0; i < 8; ++i) { e[i] = __expf(vals[i] - mx); sum += e[i]; }
    #pragma unroll
    for (int off = 1; off < 64; off <<= 1) sum += __shfl_xor(sum, off);
    if (lane == 0) red[4 + wave] = sum;
    __syncthreads();
    sum = red[4] + red[5] + red[6] + red[7];
    float inv = 1.0f / sum;
    #pragma unroll
    for (int i = 0; i < 8; ++i) attn[b * S + i * 256 + tid] = e[i] * inv;
}

// K4: opart partial weighted sums over 16 s-chunks of 128, 2-way s-split.
// AMODE 0: bf16 encb; AMODE 1: fp32 enc (fallback).
template<int AMODE>
__global__ __launch_bounds__(256) void k4_partial(
    const float* __restrict__ enc, const __hip_bfloat16* __restrict__ encb,
    const float* __restrict__ attn, const int* __restrict__ seq,
    float* __restrict__ opart)
{
    int c = blockIdx.x, b = blockIdx.y, tid = threadIdx.x;
    int base_s = c * 128;
    int len = seq[b];
    if (AMODE == 0) {
        int e0 = (tid & 127) * 8;
        int so = tid >> 7;
        float av[8];
        #pragma unroll
        for (int j = 0; j < 8; ++j) av[j] = 0.f;
        if (base_s < len) {
            int s_end = min(128, len - base_s);
            for (int s = so; s < s_end; s += 2) {
                float w = attn[b * S + base_s + s];
                bf16x8_t u = *(const bf16x8_t*)(encb +
                    (((size_t)b * S + base_s + s) << 10) + e0);
                #pragma unroll
                for (int j = 0; j < 8; ++j) av[j] += w * b2f(u[j]);
            }
        }
        float* dst = opart + (((size_t)(b * 16 + c) * 2 + so) << 10) + e0;
        *(float4*)dst       = make_float4(av[0], av[1], av[2], av[3]);
        *(float4*)(dst + 4) = make_float4(av[4], av[5], av[6], av[7]);
    } else {
        float4 acc = make_float4(0.f, 0.f, 0.f, 0.f);
        if (base_s < len) {
            int s_end = min(128, len - base_s);
            const float* ep = enc + (((size_t)b * S + base_s) << 10) + tid * 4;
            const float* ap = attn + b * S + base_s;
            for (int s = 0; s < s_end; ++s) {
                float w = ap[s];
                float4 ev = *(const float4*)ep;
                ep += E;
                acc.x += w * ev.x; acc.y += w * ev.y;
                acc.z += w * ev.z; acc.w += w * ev.w;
            }
        }
        float* dst = opart + (((size_t)(b * 16 + c) * 2) << 10) + tid * 4;
        *(float4*)dst = acc;
        float* dst2 = opart + (((size_t)(b * 16 + c) * 2 + 1) << 10) + tid * 4;
        *(float4*)dst2 = make_float4(0.f, 0.f, 0.f, 0.f);
    }
}

// K5: out[b][e] = sum over 32 partials
__global__ __launch_bounds__(256) void k5_reduce(
    const float* __restrict__ opart, float* __restrict__ out)
{
    int gid = blockIdx.x * 256 + threadIdx.x;  // 32768 = B*E
    int b = gid >> 10, e = gid & 1023;
    float s = 0.f;
    #pragma unroll
    for (int c = 0; c < 32; ++c) s += opart[((size_t)(b * 32 + c) << 10) + e];
    out[gid] = s;
}

extern "C" void kernel_launch(void* const* d_in, const int* in_sizes, int n_in,
                              void* d_out, int out_size, void* d_ws, size_t ws_size,
                              hipStream_t stream)
{
    const float* enc = (const float*)d_in[0];
    const int*   seq = (const int*)d_in[1];
    const float* dec = (const float*)d_in[2];
    const float* W   = (const float*)d_in[3];
    const float* v   = (const float*)d_in[4];

    float* out  = (float*)d_out;            // (B, E)
    float* attn = out + B * E;              // (B, S)

    float* dec_proj = (float*)d_ws;                         // B*H
    float* part     = dec_proj + B * H;                     // B*S*16
    float* opart    = part + (size_t)B * S * 16;            // B*32*1024
    __hip_bfloat16* Wb = (__hip_bfloat16*)(opart + (size_t)B * 32 * 1024);
    __hip_bfloat16* encb = Wb + (size_t)H * E;              // B*S*E bf16

    const size_t need = (size_t)(B * H + B * S * 16 + B * 32 * 1024) * 4
                      + (size_t)H * E * 2 + (size_t)B * S * E * 2;
    const bool use_encb = ws_size >= need;

    if (use_encb) {
        hipLaunchKernelGGL(kfused0, dim3(2560), dim3(256), 0, stream,
                           W, dec, enc, seq, Wb, dec_proj, encb);
        hipLaunchKernelGGL(k2_mfma<0>, dim3(4096), dim3(256), 0, stream,
                           enc, encb, Wb, v, dec_proj, seq, part);
    } else {
        hipLaunchKernelGGL(kfused0, dim3(2048), dim3(256), 0, stream,
                           W, dec, enc, seq, Wb, dec_proj, encb);
        hipLaunchKernelGGL(k2_mfma<2>, dim3(4096), dim3(256), 0, stream,
                           enc, encb, Wb, v, dec_proj, seq, part);
    }
    hipLaunchKernelGGL(k3_softmax, dim3(B), dim3(256), 0, stream,
                       part, seq, attn);
    if (use_encb) {
        hipLaunchKernelGGL(k4_partial<0>, dim3(16, B), dim3(256), 0, stream,
                           enc, encb, attn, seq, opart);
    } else {
        hipLaunchKernelGGL(k4_partial<1>, dim3(16, B), dim3(256), 0, stream,
                           enc, encb, attn, seq, opart);
    }
    hipLaunchKernelGGL(k5_reduce, dim3(B * E / 256), dim3(256), 0, stream,
                       opart, out);
}

// Round 13
// 214.022 us; speedup vs baseline: 1.1361x; 1.1361x over previous
//
#include <hip/hip_runtime.h>
#include <hip/hip_bf16.h>

#define B 32
#define S 2048
#define E 1024
#define H 1024
#define MASK_VAL -50000.0f

typedef __attribute__((ext_vector_type(8))) short bf16x8_t;
typedef __attribute__((ext_vector_type(4))) float f32x4_t;

__device__ __forceinline__ float fast_tanh(float x) {
    float a = fabsf(x);
    float e = __expf(-2.0f * a);
    float t = (1.0f - e) * __builtin_amdgcn_rcpf(1.0f + e);
    return copysignf(t, x);
}

__device__ __forceinline__ float b2f(short s) {
    return __uint_as_float(((unsigned)(unsigned short)s) << 16);
}

__device__ __forceinline__ bf16x8_t cvt8(const float4 f0, const float4 f1) {
    union { bf16x8_t s8; __hip_bfloat162 h[4]; } u;
    u.h[0] = __float22bfloat162_rn(make_float2(f0.x, f0.y));
    u.h[1] = __float22bfloat162_rn(make_float2(f0.z, f0.w));
    u.h[2] = __float22bfloat162_rn(make_float2(f1.x, f1.y));
    u.h[3] = __float22bfloat162_rn(make_float2(f1.z, f1.w));
    return u.s8;
}

__device__ __forceinline__ void gload16(const void* g, void* l) {
    __builtin_amdgcn_global_load_lds(
        (const __attribute__((address_space(1))) void*)g,
        (__attribute__((address_space(3))) void*)l, 16, 0, 0);
}

// kfused0: [0,1024) W[:, :1024] -> bf16 Wb (coalesced);
//          [1024,2048) dec_proj: one h/block, W_dec row staged in LDS,
//          32 b-dots with 8-lane chunk reduce (coalesced);
//          [2048,2560) enc -> bf16 encb, active 128-row tiles only.
__global__ __launch_bounds__(256) void kfused0(
    const float* __restrict__ W, const float* __restrict__ dec,
    const float* __restrict__ enc, const int* __restrict__ seq,
    __hip_bfloat16* __restrict__ Wb, float* __restrict__ dec_proj,
    __hip_bfloat16* __restrict__ encb)
{
    int blk = blockIdx.x, tid = threadIdx.x;
    if (blk < 1024) {
        int idx = (blk * 256 + tid) * 4;   // over H*E
        int h = idx >> 10, e = idx & 1023;
        float4 f = *(const float4*)(W + (size_t)h * 2048 + e);
        __hip_bfloat162 p0 = __float22bfloat162_rn(make_float2(f.x, f.y));
        __hip_bfloat162 p1 = __float22bfloat162_rn(make_float2(f.z, f.w));
        *reinterpret_cast<__hip_bfloat162*>(Wb + idx)     = p0;
        *reinterpret_cast<__hip_bfloat162*>(Wb + idx + 2) = p1;
    } else if (blk < 2048) {
        int h = blk - 1024;                 // 0..1023
        __shared__ float4 wlds[256];
        wlds[tid] = *(const float4*)(W + (size_t)h * 2048 + 1024 + tid * 4);
        __syncthreads();
        int b = tid >> 3, chunk = tid & 7;  // 32 b x 8 chunks of 128 elems
        const float4* dd = (const float4*)(dec + b * 1024 + chunk * 128);
        float acc = 0.f;
        #pragma unroll
        for (int i = 0; i < 32; ++i) {
            float4 w4 = wlds[chunk * 32 + i];
            float4 d4 = dd[i];
            acc += w4.x * d4.x + w4.y * d4.y + w4.z * d4.z + w4.w * d4.w;
        }
        acc += __shfl_xor(acc, 1);
        acc += __shfl_xor(acc, 2);
        acc += __shfl_xor(acc, 4);
        if (chunk == 0) dec_proj[b * H + h] = acc;
    } else {
        int g = blk - 2048;                 // 512: 16 s-chunks x 32 b
        int c = g & 15, b = g >> 4;
        if (c * 128 >= seq[b]) return;
        size_t base = ((size_t)b * S + c * 128) << 10;
        const float* src = enc + base;
        __hip_bfloat16* dst = encb + base;
        #pragma unroll 4
        for (int it = 0; it < 64; ++it) {
            int idx = it * 2048 + tid * 8;
            float4 f0 = *(const float4*)(src + idx);
            float4 f1 = *(const float4*)(src + idx + 4);
            *(bf16x8_t*)(dst + idx) = cvt8(f0, f1);
        }
    }
}

// K2: 128(s) x 128(h) tile, BK=64, K=1024 -- round-11 structure (2-phase
// dbuf, 1 barrier/K-step, XOR swizzle (row&7)<<4, LDS 64 KiB) but with
// 512 threads (8 waves, 2x4 grid, 64x32 per wave). 2 blocks/CU still fit
// (128 KiB LDS) -> 16 waves/CU instead of 8: doubled TLP to hide the
// per-step vmcnt drain, with no extra barriers and no layout change.
// MODE 0: A+B via global_load_lds (encb, Wb). MODE 2: A reg-staged fp32.
// Grid 4096: pair=(bid>>6)*8+(bid&7); ht=(bid>>3)&7 -> the 8 ht-blocks of
// one (b,st) are 8 apart -> same XCD -> A-tile L2 reuse.
template<int MODE>
__global__ __launch_bounds__(512, 2) void k2_mfma(
    const float* __restrict__ enc, const __hip_bfloat16* __restrict__ encb,
    const __hip_bfloat16* __restrict__ Wb, const float* __restrict__ v,
    const float* __restrict__ dec_proj, const int* __restrict__ seq,
    float* __restrict__ part)
{
    const int bid  = blockIdx.x;
    const int pair = (bid >> 6) * 8 + (bid & 7);   // 0..511 = 16 s-tiles x 32 b
    const int ht   = (bid >> 3) & 7;
    const int b    = pair >> 4;
    const int s0   = (pair & 15) * 128;
    if (s0 >= seq[b]) return;
    const int h0 = ht * 128;

    const int tid  = threadIdx.x;
    const int wave = tid >> 6;                 // 0..7
    const int lane = tid & 63;
    const int wr = wave >> 2, wc = wave & 3;   // 2 x 4 wave grid
    const int cr = lane & 15, cg = lane >> 4;

    __shared__ __hip_bfloat16 Al[2][128 * 64];
    __shared__ __hip_bfloat16 Bl[2][128 * 64];

    const int colb  = (tid & 7) * 16;   // byte col within 128B LDS row
    const int rbase = tid >> 3;         // 0..63

    f32x4_t acc[4][2];
    #pragma unroll
    for (int m = 0; m < 4; ++m)
        #pragma unroll
        for (int n = 0; n < 2; ++n)
            acc[m][n] = (f32x4_t){0.f, 0.f, 0.f, 0.f};

    auto stage = [&](int buf, int kt) {
        #pragma unroll
        for (int i = 0; i < 2; ++i) {
            const int row   = i * 64 + rbase;
            const int scolb = colb ^ ((row & 7) << 4);
            const __hip_bfloat16* bg =
                Wb + (((size_t)(h0 + row)) << 10) + kt * 64 + (scolb >> 1);
            gload16(bg, (char*)&Bl[buf][0] + (i * 512 + tid) * 16);
            if (MODE == 0) {
                const __hip_bfloat16* ag =
                    encb + (((size_t)b * S + s0 + row) << 10) + kt * 64 + (scolb >> 1);
                gload16(ag, (char*)&Al[buf][0] + (i * 512 + tid) * 16);
            } else {
                const float* af =
                    enc + (((size_t)b * S + s0 + row) << 10) + kt * 64 + (tid & 7) * 8;
                bf16x8_t v8 = cvt8(*(const float4*)af, *(const float4*)(af + 4));
                *(bf16x8_t*)((char*)&Al[buf][0] + row * 128 + scolb) = v8;
            }
        }
    };

    stage(0, 0);
    __syncthreads();
    int cur = 0;
    for (int kt = 0; kt < 16; ++kt) {
        if (kt < 15) stage(cur ^ 1, kt + 1);   // flies under the MFMAs below
        bf16x8_t afr[2][4], bfr[2][2];
        #pragma unroll
        for (int ks = 0; ks < 2; ++ks) {
            #pragma unroll
            for (int m = 0; m < 4; ++m) {
                const int arow  = wr * 64 + m * 16 + cr;
                const int acolb = (ks * 64 + cg * 16) ^ ((arow & 7) << 4);
                afr[ks][m] = *(const bf16x8_t*)((const char*)&Al[cur][0] + arow * 128 + acolb);
            }
            #pragma unroll
            for (int n = 0; n < 2; ++n) {
                const int brow  = wc * 32 + n * 16 + cr;
                const int bcolb = (ks * 64 + cg * 16) ^ ((brow & 7) << 4);
                bfr[ks][n] = *(const bf16x8_t*)((const char*)&Bl[cur][0] + brow * 128 + bcolb);
            }
        }
        #pragma unroll
        for (int ks = 0; ks < 2; ++ks)
            #pragma unroll
            for (int m = 0; m < 4; ++m)
                #pragma unroll
                for (int n = 0; n < 2; ++n)
                    acc[m][n] = __builtin_amdgcn_mfma_f32_16x16x32_bf16(
                        afr[ks][m], bfr[ks][n], acc[m][n], 0, 0, 0);
        __syncthreads();   // drains vmcnt+lgkmcnt: next buf ready, cur consumed
        cur ^= 1;
    }

    // Epilogue: t = v*tanh(acc + dec_proj); reduce over n frags + 16 cr lanes.
    float vv[2], dp[2];
    #pragma unroll
    for (int n = 0; n < 2; ++n) {
        int h = h0 + wc * 32 + n * 16 + cr;
        vv[n] = v[h];
        dp[n] = dec_proj[b * H + h];
    }
    #pragma unroll
    for (int m = 0; m < 4; ++m) {
        #pragma unroll
        for (int j = 0; j < 4; ++j) {
            float t = 0.f;
            #pragma unroll
            for (int n = 0; n < 2; ++n)
                t += vv[n] * fast_tanh(acc[m][n][j] + dp[n]);
            t += __shfl_xor(t, 1);
            t += __shfl_xor(t, 2);
            t += __shfl_xor(t, 4);
            t += __shfl_xor(t, 8);
            if (cr == 0) {
                int srow = s0 + wr * 64 + m * 16 + cg * 4 + j;
                part[(size_t)(b * S + srow) * 32 + ht * 4 + wc] = t;
            }
        }
    }
}

// K3: sum 32 partials -> logit; masked softmax over s per batch
__global__ __launch_bounds__(256) void k3_softmax(
    const float* __restrict__ part, const int* __restrict__ seq,
    float* __restrict__ attn)
{
    int b = blockIdx.x, tid = threadIdx.x;
    int len = seq[b];
    float vals[8];
    float mx = -3.4e38f;
    #pragma unroll
    for (int i = 0; i < 8; ++i) {
        int s = i * 256 + tid;
        float x = MASK_VAL;
        if (s < len) {
            const f32x4_t* p = (const f32x4_t*)&part[(size_t)(b * S + s) * 32];
            float acc = 0.f;
            #pragma unroll
            for (int q = 0; q < 8; ++q) {
                f32x4_t a = p[q];
                acc += (a[0] + a[1]) + (a[2] + a[3]);
            }
            x = acc;
        }
        vals[i] = x;
        mx = fmaxf(mx, x);
    }
    #pragma unroll
    for (int off = 1; off < 64; off <<= 1) mx = fmaxf(mx, __shfl_xor(mx, off));
    __shared__ float red[8];
    int wave = tid >> 6, lane = tid & 63;
    if (lane == 0) red[wave] = mx;
    __syncthreads();
    mx = fmaxf(fmaxf(red[0], red[1]), fmaxf(red[2], red[3]));
    float e[8];
    float sum = 0.f;
    #pragma unroll
    for (int i = 0; i < 8; ++i) { e[i] = __expf(vals[i] - mx); sum += e[i]; }
    #pragma unroll
    for (int off = 1; off < 64; off <<= 1) sum += __shfl_xor(sum, off);
    if (lane == 0) red[4 + wave] = sum;
    __syncthreads();
    sum = red[4] + red[5] + red[6] + red[7];
    float inv = 1.0f / sum;
    #pragma unroll
    for (int i = 0; i < 8; ++i) attn[b * S + i * 256 + tid] = e[i] * inv;
}

// K4: opart partial weighted sums over 16 s-chunks of 128, 2-way s-split.
// AMODE 0: bf16 encb; AMODE 1: fp32 enc (fallback).
template<int AMODE>
__global__ __launch_bounds__(256) void k4_partial(
    const float* __restrict__ enc, const __hip_bfloat16* __restrict__ encb,
    const float* __restrict__ attn, const int* __restrict__ seq,
    float* __restrict__ opart)
{
    int c = blockIdx.x, b = blockIdx.y, tid = threadIdx.x;
    int base_s = c * 128;
    int len = seq[b];
    if (AMODE == 0) {
        int e0 = (tid & 127) * 8;
        int so = tid >> 7;
        float av[8];
        #pragma unroll
        for (int j = 0; j < 8; ++j) av[j] = 0.f;
        if (base_s < len) {
            int s_end = min(128, len - base_s);
            for (int s = so; s < s_end; s += 2) {
                float w = attn[b * S + base_s + s];
                bf16x8_t u = *(const bf16x8_t*)(encb +
                    (((size_t)b * S + base_s + s) << 10) + e0);
                #pragma unroll
                for (int j = 0; j < 8; ++j) av[j] += w * b2f(u[j]);
            }
        }
        float* dst = opart + (((size_t)(b * 16 + c) * 2 + so) << 10) + e0;
        *(float4*)dst       = make_float4(av[0], av[1], av[2], av[3]);
        *(float4*)(dst + 4) = make_float4(av[4], av[5], av[6], av[7]);
    } else {
        float4 acc = make_float4(0.f, 0.f, 0.f, 0.f);
        if (base_s < len) {
            int s_end = min(128, len - base_s);
            const float* ep = enc + (((size_t)b * S + base_s) << 10) + tid * 4;
            const float* ap = attn + b * S + base_s;
            for (int s = 0; s < s_end; ++s) {
                float w = ap[s];
                float4 ev = *(const float4*)ep;
                ep += E;
                acc.x += w * ev.x; acc.y += w * ev.y;
                acc.z += w * ev.z; acc.w += w * ev.w;
            }
        }
        float* dst = opart + (((size_t)(b * 16 + c) * 2) << 10) + tid * 4;
        *(float4*)dst = acc;
        float* dst2 = opart + (((size_t)(b * 16 + c) * 2 + 1) << 10) + tid * 4;
        *(float4*)dst2 = make_float4(0.f, 0.f, 0.f, 0.f);
    }
}

// K5: out[b][e] = sum over 32 partials
__global__ __launch_bounds__(256) void k5_reduce(
    const float* __restrict__ opart, float* __restrict__ out)
{
    int gid = blockIdx.x * 256 + threadIdx.x;  // 32768 = B*E
    int b = gid >> 10, e = gid & 1023;
    float s = 0.f;
    #pragma unroll
    for (int c = 0; c < 32; ++c) s += opart[((size_t)(b * 32 + c) << 10) + e];
    out[gid] = s;
}

extern "C" void kernel_launch(void* const* d_in, const int* in_sizes, int n_in,
                              void* d_out, int out_size, void* d_ws, size_t ws_size,
                              hipStream_t stream)
{
    const float* enc = (const float*)d_in[0];
    const int*   seq = (const int*)d_in[1];
    const float* dec = (const float*)d_in[2];
    const float* W   = (const float*)d_in[3];
    const float* v   = (const float*)d_in[4];

    float* out  = (float*)d_out;            // (B, E)
    float* attn = out + B * E;              // (B, S)

    float* dec_proj = (float*)d_ws;                         // B*H
    float* part     = dec_proj + B * H;                     // B*S*32
    float* opart    = part + (size_t)B * S * 32;            // B*32*1024
    __hip_bfloat16* Wb = (__hip_bfloat16*)(opart + (size_t)B * 32 * 1024);
    __hip_bfloat16* encb = Wb + (size_t)H * E;              // B*S*E bf16

    const size_t need = (size_t)(B * H + B * S * 32 + B * 32 * 1024) * 4
                      + (size_t)H * E * 2 + (size_t)B * S * E * 2;
    const bool use_encb = ws_size >= need;

    if (use_encb) {
        hipLaunchKernelGGL(kfused0, dim3(2560), dim3(256), 0, stream,
                           W, dec, enc, seq, Wb, dec_proj, encb);
        hipLaunchKernelGGL(k2_mfma<0>, dim3(4096), dim3(512), 0, stream,
                           enc, encb, Wb, v, dec_proj, seq, part);
    } else {
        hipLaunchKernelGGL(kfused0, dim3(2048), dim3(256), 0, stream,
                           W, dec, enc, seq, Wb, dec_proj, encb);
        hipLaunchKernelGGL(k2_mfma<2>, dim3(4096), dim3(512), 0, stream,
                           enc, encb, Wb, v, dec_proj, seq, part);
    }
    hipLaunchKernelGGL(k3_softmax, dim3(B), dim3(256), 0, stream,
                       part, seq, attn);
    if (use_encb) {
        hipLaunchKernelGGL(k4_partial<0>, dim3(16, B), dim3(256), 0, stream,
                           enc, encb, attn, seq, opart);
    } else {
        hipLaunchKernelGGL(k4_partial<1>, dim3(16, B), dim3(256), 0, stream,
                           enc, encb, attn, seq, opart);
    }
    hipLaunchKernelGGL(k5_reduce, dim3(B * E / 256), dim3(256), 0, stream,
                       opart, out);
}